// Round 1
// 1233.761 us; speedup vs baseline: 1.3743x; 1.3743x over previous
//
#include <hip/hip_runtime.h>
#include <hip/hip_bf16.h>
#include <cstdint>
#include <cstddef>

typedef __bf16 bf16;
typedef __attribute__((ext_vector_type(8))) __bf16 bf16x8;
typedef __attribute__((ext_vector_type(4))) __bf16 bf16x4;
typedef __attribute__((ext_vector_type(4))) float f32x4;

// ---------------------------------------------------------------------------
// async global->LDS, 16B per lane (wave-uniform LDS base + lane*16)
__device__ __forceinline__ void gload_lds16(const void* g, void* l) {
  __builtin_amdgcn_global_load_lds(
      (const __attribute__((address_space(1))) uint32_t*)(uintptr_t)g,
      (__attribute__((address_space(3))) uint32_t*)(uintptr_t)l, 16, 0, 0);
}

// ---------------------------------------------------------------------------
// Batched NT GEMM: up to 4 independent problems per launch, selected by
// blockIdx.z. Purpose: tall-skinny shapes (M=4096, N~1024) give 224-320
// workgroups = 1 block/CU resident -> barrier-drain stall fully exposed
// (m102: 256-block grids run ~320 TF vs 833 TF at 1024 blocks). Batching
// independent pairs doubles residency with decorrelated phases.
// C[M=4096, Npad] = act(A[M,K] * Bt[Npad,K]^T + bias); act runtime
// (0=none,1=tanh,2=sigmoid). 128x128 tile, BK=32, 4 waves in 2x2, each wave
// 4x4 mfma_f32_16x16x32_bf16.
struct GProb {
  const bf16* A; const bf16* Bt; const float* bias;
  float* Cf; bf16* Cb;
  int K, Npad, ldcf, ldcb, Ntrue, act;
};
struct GBatch { GProb p[4]; };

__global__ __launch_bounds__(256, 2)
void gemm_nt_batch(GBatch b)
{
  const GProb P = b.p[blockIdx.z];
  const long bn = (long)blockIdx.x * 128;
  if (bn >= P.Npad) return;          // uniform whole-block exit (before any barrier)

  __shared__ __align__(16) bf16 As[128 * 32];
  __shared__ __align__(16) bf16 Bs[128 * 32];

  const int K    = P.K;
  const int tid  = threadIdx.x;
  const int lane = tid & 63, wave = tid >> 6;
  const int wr = wave >> 1, wc = wave & 1;
  const int l15 = lane & 15, quad = lane >> 4;
  const long bm = (long)blockIdx.y * 128;

  // staging: slot = s*256 + tid; row=slot/4, chunk-slot=slot%4,
  // global chunk = cslot ^ (row&3)  (XOR swizzle; LDS slot order == lane order)
  long aoff[2], boff[2];
  int ldsoff[2];
#pragma unroll
  for (int s = 0; s < 2; ++s) {
    int slot = s * 256 + tid;
    int row = slot >> 2, cs = slot & 3;
    int gc = cs ^ (row & 3);
    aoff[s] = (bm + row) * (long)K + gc * 8;
    boff[s] = (bn + row) * (long)K + gc * 8;
    ldsoff[s] = (s * 256 + wave * 64) * 8;   // wave-uniform base (elements)
  }

  // fragment LDS offsets: row r needs chunk q at slot q^(r&3); r&3 == lane&3
  const int cfr = (quad ^ (lane & 3)) * 8;
  int afr[4], bfr[4];
#pragma unroll
  for (int i = 0; i < 4; ++i) {
    afr[i] = (wr * 64 + i * 16 + l15) * 32 + cfr;
    bfr[i] = (wc * 64 + i * 16 + l15) * 32 + cfr;
  }

  f32x4 acc[4][4];
#pragma unroll
  for (int i = 0; i < 4; ++i)
#pragma unroll
    for (int j = 0; j < 4; ++j) acc[i][j] = {0.f, 0.f, 0.f, 0.f};

  for (int k0 = 0; k0 < K; k0 += 32) {
    __syncthreads();                       // protect LDS from previous readers
    gload_lds16(P.A + aoff[0] + k0, As + ldsoff[0]);
    gload_lds16(P.A + aoff[1] + k0, As + ldsoff[1]);
    gload_lds16(P.Bt + boff[0] + k0, Bs + ldsoff[0]);
    gload_lds16(P.Bt + boff[1] + k0, Bs + ldsoff[1]);
    __syncthreads();                       // compiler drains vmcnt before barrier

    bf16x8 av[4], bv[4];
#pragma unroll
    for (int i = 0; i < 4; ++i) av[i] = *(const bf16x8*)(As + afr[i]);
#pragma unroll
    for (int j = 0; j < 4; ++j) bv[j] = *(const bf16x8*)(Bs + bfr[j]);
#pragma unroll
    for (int i = 0; i < 4; ++i)
#pragma unroll
      for (int j = 0; j < 4; ++j)
        acc[i][j] = __builtin_amdgcn_mfma_f32_16x16x32_bf16(av[i], bv[j], acc[i][j], 0, 0, 0);
  }

  // epilogue: C/D layout col=lane&15, row=quad*4+reg
  const long row0 = bm + wr * 64 + quad * 4;
  const long col0 = bn + wc * 64 + l15;
  const int act = P.act;
#pragma unroll
  for (int i = 0; i < 4; ++i) {
#pragma unroll
    for (int j = 0; j < 4; ++j) {
      long c = col0 + j * 16;
      float bb = P.bias ? P.bias[c] : 0.f;
#pragma unroll
      for (int t = 0; t < 4; ++t) {
        long r = row0 + i * 16 + t;
        float v = acc[i][j][t] + bb;
        if (act == 1) v = tanhf(v);
        else if (act == 2) v = 1.f / (1.f + __expf(-v));
        if (P.Cf && c < P.Ntrue) P.Cf[r * P.ldcf + c] = v;
        if (P.Cb) P.Cb[r * P.ldcb + c] = (bf16)v;
      }
    }
  }
}

// ---------------------------------------------------------------------------
// Batched padded transpose: dst[P x Q] = src^T zero-padded.
// Up to 14 problems per launch, flat 1D block enumeration (no idle blocks).
struct TrBatch {
  const void* src[14]; bf16* dst[14];
  int R[14], C[14], Q[14], nbx[14], isb[14];
  int blkStart[15];
  int nprob;
};

__global__ void tr_batch(TrBatch a)
{
  __shared__ float tile[32][33];
  int pi = 0, b = blockIdx.x;
  while (b >= a.blkStart[pi + 1]) ++pi;
  const int rel = b - a.blkStart[pi];
  const int nbx = a.nbx[pi];
  const int q0 = (rel % nbx) * 32;       // src-row block
  const int p0 = (rel / nbx) * 32;       // src-col block
  const int R = a.R[pi], C = a.C[pi], Q = a.Q[pi];
  const bool isb = a.isb[pi] != 0;
  const void* src = a.src[pi];
  const int tx = threadIdx.x & 31, ty = threadIdx.x >> 5;
#pragma unroll
  for (int y = ty; y < 32; y += 8) {
    int r = q0 + y, c = p0 + tx;
    float v = 0.f;
    if (r < R && c < C)
      v = isb ? (float)((const bf16*)src)[(long)r * C + c]
              : ((const float*)src)[(long)r * C + c];
    tile[y][tx] = v;
  }
  __syncthreads();
  bf16* dst = a.dst[pi];
#pragma unroll
  for (int y = ty; y < 32; y += 8)
    dst[(long)(p0 + y) * Q + (q0 + tx)] = (bf16)tile[tx][y];
}

// fp32 -> bf16, two buffers per launch (blockIdx.z), n % 4 == 0
struct CvtB { const float* s[2]; bf16* d[2]; };
__global__ void cvt_batch(CvtB cb, long n)
{
  const float* s = cb.s[blockIdx.z];
  bf16* d = cb.d[blockIdx.z];
  long i = ((long)blockIdx.x * blockDim.x + threadIdx.x) * 4;
  if (i >= n) return;
  float4 v = *(const float4*)(s + i);
  bf16x4 o = {(bf16)v.x, (bf16)v.y, (bf16)v.z, (bf16)v.w};
  *(bf16x4*)(d + i) = o;
}

// z = (we0*h20 + we1*h21)/(we0+we1); fp32 [4096,819] out + bf16 [4096,896]
__global__ void zkern(const float* __restrict__ h20, const float* __restrict__ h21,
                      const float* __restrict__ we, float* __restrict__ zout,
                      bf16* __restrict__ zb)
{
  const int n = blockIdx.x;
  const float w0 = we[n * 2], w1 = we[n * 2 + 1];
  const float inv = 1.f / (w0 + w1);
  for (int c = threadIdx.x; c < 896; c += 256) {
    float v = (w0 * h20[(long)n * 896 + c] + w1 * h21[(long)n * 896 + c]) * inv;
    zb[(long)n * 896 + c] = (bf16)v;
    if (c < 819) zout[(long)n * 819 + c] = v;
  }
}

// Student-t q per row (one wave per row). NO atomics — colsum done separately.
__global__ void qkern(const float* __restrict__ z, const float* __restrict__ cl,
                      float* __restrict__ qout)
{
  const int n = blockIdx.x;
  const int lane = threadIdx.x;
  float d0 = 0, d1 = 0, d2 = 0, d3 = 0, d4 = 0;
  for (int s = lane; s < 819; s += 64) {
    float zv = z[(long)n * 819 + s];
    float t0 = zv - cl[0 * 819 + s]; d0 += t0 * t0;
    float t1 = zv - cl[1 * 819 + s]; d1 += t1 * t1;
    float t2 = zv - cl[2 * 819 + s]; d2 += t2 * t2;
    float t3 = zv - cl[3 * 819 + s]; d3 += t3 * t3;
    float t4 = zv - cl[4 * 819 + s]; d4 += t4 * t4;
  }
#pragma unroll
  for (int off = 32; off > 0; off >>= 1) {
    d0 += __shfl_xor(d0, off);
    d1 += __shfl_xor(d1, off);
    d2 += __shfl_xor(d2, off);
    d3 += __shfl_xor(d3, off);
    d4 += __shfl_xor(d4, off);
  }
  if (lane == 0) {
    float q0 = 1.f / (1.f + d0), q1 = 1.f / (1.f + d1), q2 = 1.f / (1.f + d2);
    float q3 = 1.f / (1.f + d3), q4 = 1.f / (1.f + d4);
    float inv = 1.f / (q0 + q1 + q2 + q3 + q4);
    float* qr = qout + (long)n * 5;
    qr[0] = q0 * inv; qr[1] = q1 * inv; qr[2] = q2 * inv;
    qr[3] = q3 * inv; qr[4] = q4 * inv;
  }
}

__global__ void colsum_kern(const float* __restrict__ q, float* __restrict__ colsum)
{
  __shared__ float red[256];
  const int k = blockIdx.x;
  float s = 0.f;
  for (int n = threadIdx.x; n < 4096; n += 256) s += q[(long)n * 5 + k];
  red[threadIdx.x] = s;
  __syncthreads();
  for (int w = 128; w > 0; w >>= 1) {
    if (threadIdx.x < w) red[threadIdx.x] += red[threadIdx.x + w];
    __syncthreads();
  }
  if (threadIdx.x == 0) colsum[k] = red[0];
}

__global__ void pkern(const float* __restrict__ q, const float* __restrict__ colsum,
                      float* __restrict__ p)
{
  int n = blockIdx.x * blockDim.x + threadIdx.x;
  if (n >= 4096) return;
  float w[5], s = 0.f;
#pragma unroll
  for (int k = 0; k < 5; ++k) {
    float qv = q[(long)n * 5 + k];
    w[k] = qv * qv / colsum[k];
    s += w[k];
  }
  float inv = 1.f / s;
#pragma unroll
  for (int k = 0; k < 5; ++k) p[(long)n * 5 + k] = w[k] * inv;
}

struct BiasArgs {
  const float* src[8];
  float* dst[8];
  int n[8];
  int np[8];
};

__global__ void biaspad(BiasArgs a)
{
  int b = blockIdx.x;
  for (int i = threadIdx.x; i < a.np[b]; i += blockDim.x)
    a.dst[b][i] = (i < a.n[b]) ? a.src[b][i] : 0.f;
}

// ---------------------------------------------------------------------------
extern "C" void kernel_launch(void* const* d_in, const int* in_sizes, int n_in,
                              void* d_out, int out_size, void* d_ws, size_t ws_size,
                              hipStream_t stream)
{
  (void)in_sizes; (void)n_in; (void)out_size; (void)ws_size;
  const float* x0    = (const float*)d_in[0];
  const float* x1    = (const float*)d_in[1];
  const float* we    = (const float*)d_in[2];
  const float* g0    = (const float*)d_in[3];
  const float* g1    = (const float*)d_in[4];
  const float* We1_0 = (const float*)d_in[5];
  const float* be1_0 = (const float*)d_in[6];
  const float* We2_0 = (const float*)d_in[7];
  const float* be2_0 = (const float*)d_in[8];
  const float* We1_1 = (const float*)d_in[9];
  const float* be1_1 = (const float*)d_in[10];
  const float* We2_1 = (const float*)d_in[11];
  const float* be2_1 = (const float*)d_in[12];
  const float* Wd1_0 = (const float*)d_in[13];
  const float* bd1_0 = (const float*)d_in[14];
  const float* Wd2_0 = (const float*)d_in[15];
  const float* bd2_0 = (const float*)d_in[16];
  const float* Wd1_1 = (const float*)d_in[17];
  const float* bd1_1 = (const float*)d_in[18];
  const float* Wd2_1 = (const float*)d_in[19];
  const float* bd2_1 = (const float*)d_in[20];
  const float* Ww0   = (const float*)d_in[21];
  const float* Ww1   = (const float*)d_in[22];
  const float* Wf0   = (const float*)d_in[23];
  const float* Wf1   = (const float*)d_in[24];
  const float* clus  = (const float*)d_in[25];
  float* out = (float*)d_out;

  const size_t OFF_REC0 = 0;
  const size_t OFF_REC1 = 4194304;
  const size_t OFF_ADJ0 = 9437184;
  const size_t OFF_ADJ1 = 26214400;
  const size_t OFF_Z    = 42991616;
  const size_t OFF_P    = 46346240;
  const size_t OFF_Q    = 46366720;
  const size_t OFF_CL   = 46387200;

  char* ws = (char*)d_ws;
  size_t off = 0;
  auto alloc = [&](size_t bytes) -> void* {
    off = (off + 255) & ~(size_t)255;
    void* p = ws + off;
    off += bytes;
    return p;
  };
  const long N = 4096;
  bf16* g0b   = (bf16*)alloc((size_t)N * 4096 * 2);
  bf16* g1b   = (bf16*)alloc((size_t)N * 4096 * 2);
  bf16* BTe10 = (bf16*)alloc((size_t)896 * 1024 * 2);
  bf16* BTe20 = (bf16*)alloc((size_t)896 * 896 * 2);
  bf16* BTe11 = (bf16*)alloc((size_t)1024 * 1280 * 2);
  bf16* BTe21 = (bf16*)alloc((size_t)896 * 1024 * 2);
  bf16* BTd10 = (bf16*)alloc((size_t)896 * 896 * 2);
  bf16* BTd20 = (bf16*)alloc((size_t)1024 * 896 * 2);
  bf16* BTd11 = (bf16*)alloc((size_t)1024 * 896 * 2);
  bf16* BTd21 = (bf16*)alloc((size_t)1280 * 1024 * 2);
  bf16* BTw0  = (bf16*)alloc((size_t)896 * 896 * 2);
  bf16* BTw1  = (bf16*)alloc((size_t)896 * 896 * 2);
  bf16* BTf0  = (bf16*)alloc((size_t)896 * 896 * 2);
  bf16* BTf1  = (bf16*)alloc((size_t)896 * 896 * 2);
  float* pbe10 = (float*)alloc(896 * 4);
  float* pbe20 = (float*)alloc(896 * 4);
  float* pbe11 = (float*)alloc(1024 * 4);
  float* pbe21 = (float*)alloc(896 * 4);
  float* pbd10 = (float*)alloc(896 * 4);
  float* pbd20 = (float*)alloc(1024 * 4);
  float* pbd11 = (float*)alloc(1024 * 4);
  float* pbd21 = (float*)alloc(1280 * 4);
  float* h20f  = (float*)alloc((size_t)N * 896 * 4);
  float* h21f  = (float*)alloc((size_t)N * 896 * 4);
  bf16* zb     = (bf16*)alloc((size_t)N * 896 * 2);
  float* colsum = (float*)alloc(64);
  // transposed-operand buffers (reused 3-4x along the stream order)
  bf16* xT0 = (bf16*)alloc((size_t)1024 * 4096 * 2);  // x0^T / h1_0^T / t0^T / hr0^T
  bf16* xT1 = (bf16*)alloc((size_t)1280 * 4096 * 2);  // x1^T / h1_1^T / t1^T / hr1^T
  bf16* u0  = (bf16*)alloc((size_t)N * 1024 * 2);     // u0 / r0 / rin0
  bf16* u1  = (bf16*)alloc((size_t)N * 1280 * 2);     // u1 / r1 / rin1
  bf16* h0  = (bf16*)alloc((size_t)N * 896 * 2);      // h1_0 / v0 / hr0
  bf16* h1b = (bf16*)alloc((size_t)N * 1024 * 2);     // h1_1 / v1 / hr1
  bf16* y0  = (bf16*)alloc((size_t)N * 896 * 2);
  bf16* y1  = (bf16*)alloc((size_t)N * 896 * 2);
  bf16* t0b = (bf16*)alloc((size_t)N * 896 * 2);
  bf16* t1b = (bf16*)alloc((size_t)N * 896 * 2);

  // ---- input conversions (one launch) ------------------------------------
  {
    CvtB cb;
    cb.s[0] = g0; cb.d[0] = g0b;
    cb.s[1] = g1; cb.d[1] = g1b;
    cvt_batch<<<dim3(16384, 1, 2), 256, 0, stream>>>(cb, N * 4096);
  }

  // ---- all 14 transposes in one launch ------------------------------------
  {
    TrBatch tb{};
    tb.nprob = 0; tb.blkStart[0] = 0;
    auto addTr = [&](const void* s, bf16* d, int R, int C, int P, int Q, int isb) {
      int i = tb.nprob++;
      tb.src[i] = s; tb.dst[i] = d;
      tb.R[i] = R; tb.C[i] = C; tb.Q[i] = Q; tb.isb[i] = isb;
      tb.nbx[i] = Q / 32;
      tb.blkStart[i + 1] = tb.blkStart[i] + (Q / 32) * (P / 32);
    };
    addTr(x0, xT0, 4096, 1024, 1024, 4096, 0);
    addTr(x1, xT1, 4096, 1280, 1280, 4096, 0);
    addTr(We1_0, BTe10, 1024, 819, 896, 1024, 0);
    addTr(We2_0, BTe20, 819, 819, 896, 896, 0);
    addTr(We1_1, BTe11, 1280, 1024, 1024, 1280, 0);
    addTr(We2_1, BTe21, 1024, 819, 896, 1024, 0);
    addTr(Wd1_0, BTd10, 819, 819, 896, 896, 0);
    addTr(Wd2_0, BTd20, 819, 1024, 1024, 896, 0);
    addTr(Wd1_1, BTd11, 819, 1024, 1024, 896, 0);
    addTr(Wd2_1, BTd21, 1024, 1280, 1280, 1024, 0);
    addTr(Ww0, BTw0, 819, 819, 896, 896, 0);
    addTr(Ww1, BTw1, 819, 819, 896, 896, 0);
    addTr(Wf0, BTf0, 819, 819, 896, 896, 0);
    addTr(Wf1, BTf1, 819, 819, 896, 896, 0);
    tr_batch<<<tb.blkStart[tb.nprob], 256, 0, stream>>>(tb);
  }

  BiasArgs ba;
  {
    const float* bsrc[8] = {be1_0, be2_0, be1_1, be2_1, bd1_0, bd2_0, bd1_1, bd2_1};
    float* bdst[8] = {pbe10, pbe20, pbe11, pbe21, pbd10, pbd20, pbd11, pbd21};
    int bn_[8] = {819, 819, 1024, 819, 819, 1024, 1024, 1280};
    int bnp[8] = {896, 896, 1024, 896, 896, 1024, 1024, 1280};
    for (int i = 0; i < 8; ++i) { ba.src[i] = bsrc[i]; ba.dst[i] = bdst[i]; ba.n[i] = bn_[i]; ba.np[i] = bnp[i]; }
  }
  biaspad<<<8, 256, 0, stream>>>(ba);

  // ---- batched GEMM helpers ----------------------------------------------
  GBatch gb{};
  int np = 0, maxN = 0;
  auto beg = [&]() { np = 0; maxN = 0; };
  auto add = [&](const bf16* A, const bf16* Bt, const float* bias,
                 float* Cf, int ldcf, bf16* Cb, int ldcb,
                 int K, int Npad, int Ntrue, int act) {
    gb.p[np].A = A; gb.p[np].Bt = Bt; gb.p[np].bias = bias;
    gb.p[np].Cf = Cf; gb.p[np].Cb = Cb;
    gb.p[np].K = K; gb.p[np].Npad = Npad;
    gb.p[np].ldcf = ldcf; gb.p[np].ldcb = ldcb;
    gb.p[np].Ntrue = Ntrue; gb.p[np].act = act;
    ++np;
    if (Npad > maxN) maxN = Npad;
  };
  auto go = [&]() {
    gemm_nt_batch<<<dim3(maxN / 128, 32, np), 256, 0, stream>>>(gb);
  };
  auto trb2 = [&](const bf16* s0, int C0, const bf16* s1, int C1) {
    TrBatch tb{};
    tb.nprob = 2; tb.blkStart[0] = 0;
    tb.src[0] = s0; tb.dst[0] = xT0; tb.R[0] = 4096; tb.C[0] = C0; tb.Q[0] = 4096;
    tb.isb[0] = 1; tb.nbx[0] = 128; tb.blkStart[1] = 128 * (C0 / 32);
    tb.src[1] = s1; tb.dst[1] = xT1; tb.R[1] = 4096; tb.C[1] = C1; tb.Q[1] = 4096;
    tb.isb[1] = 1; tb.nbx[1] = 128; tb.blkStart[2] = tb.blkStart[1] + 128 * (C1 / 32);
    tr_batch<<<tb.blkStart[2], 256, 0, stream>>>(tb);
  };

  // ---- encoders (0 || 1) -------------------------------------------------
  beg();  // A: u = g @ x
  add(g0b, xT0, nullptr, nullptr, 0, u0, 1024, 4096, 1024, 1024, 0);
  add(g1b, xT1, nullptr, nullptr, 0, u1, 1280, 4096, 1280, 1280, 0);
  go();
  beg();  // B: h1 = tanh(u @ We1 + b)
  add(u0, BTe10, pbe10, nullptr, 0, h0, 896, 1024, 896, 896, 1);
  add(u1, BTe11, pbe11, nullptr, 0, h1b, 1024, 1280, 1024, 1024, 1);
  go();
  trb2(h0, 896, h1b, 1024);                                  // h1^T
  beg();  // C: v = g @ h1
  add(g0b, xT0, nullptr, nullptr, 0, h0, 896, 4096, 896, 896, 0);
  add(g1b, xT1, nullptr, nullptr, 0, h1b, 1024, 4096, 1024, 1024, 0);
  go();
  beg();  // D: h2 = tanh(v @ We2 + b)  (fp32 out)
  add(h0, BTe20, pbe20, h20f, 896, nullptr, 0, 896, 896, 896, 1);
  add(h1b, BTe21, pbe21, h21f, 896, nullptr, 0, 1024, 896, 896, 1);
  go();

  // ---- z -----------------------------------------------------------------
  zkern<<<4096, 256, 0, stream>>>(h20f, h21f, we, out + OFF_Z, zb);

  // ---- four z-projections in one launch ----------------------------------
  beg();  // E: y0, y1 (act0), t0, t1 (act1)
  add(zb, BTw0, nullptr, nullptr, 0, y0, 896, 896, 896, 896, 0);
  add(zb, BTw1, nullptr, nullptr, 0, y1, 896, 896, 896, 896, 0);
  add(zb, BTf0, nullptr, nullptr, 0, t0b, 896, 896, 896, 896, 1);
  add(zb, BTf1, nullptr, nullptr, 0, t1b, 896, 896, 896, 896, 1);
  go();
  beg();  // F: adj = sigmoid(y @ z^T)
  add(y0, zb, nullptr, out + OFF_ADJ0, 4096, nullptr, 0, 896, 4096, 4096, 2);
  add(y1, zb, nullptr, out + OFF_ADJ1, 4096, nullptr, 0, 896, 4096, 4096, 2);
  go();

  // ---- feature decoders (0 || 1) -----------------------------------------
  trb2(t0b, 896, t1b, 896);                                  // t^T
  beg();  // G: r = g @ t
  add(g0b, xT0, nullptr, nullptr, 0, u0, 896, 4096, 896, 896, 0);
  add(g1b, xT1, nullptr, nullptr, 0, u1, 896, 4096, 896, 896, 0);
  go();
  beg();  // H: hr = tanh(r @ Wd1 + b)
  add(u0, BTd10, pbd10, nullptr, 0, h0, 896, 896, 896, 896, 1);
  add(u1, BTd11, pbd11, nullptr, 0, h1b, 1024, 896, 1024, 1024, 1);
  go();
  trb2(h0, 896, h1b, 1024);                                  // hr^T
  beg();  // I: rin = g @ hr
  add(g0b, xT0, nullptr, nullptr, 0, u0, 896, 4096, 896, 896, 0);
  add(g1b, xT1, nullptr, nullptr, 0, u1, 1024, 4096, 1024, 1024, 0);
  go();
  beg();  // J: rec = tanh(rin @ Wd2 + b)  (fp32 out)
  add(u0, BTd20, pbd20, out + OFF_REC0, 1024, nullptr, 0, 896, 1024, 1024, 1);
  add(u1, BTd21, pbd21, out + OFF_REC1, 1280, nullptr, 0, 1024, 1280, 1280, 1);
  go();

  // ---- q / p / cluster ---------------------------------------------------
  qkern<<<4096, 64, 0, stream>>>(out + OFF_Z, clus, out + OFF_Q);
  colsum_kern<<<5, 256, 0, stream>>>(out + OFF_Q, colsum);
  pkern<<<16, 256, 0, stream>>>(out + OFF_Q, colsum, out + OFF_P);
  hipMemcpyAsync(out + OFF_CL, (const void*)clus, 4095 * sizeof(float),
                 hipMemcpyDeviceToDevice, stream);
}